// Round 1
// baseline (562.755 us; speedup 1.0000x reference)
//
#include <hip/hip_runtime.h>

// Problem constants (from reference)
#define Bx 4
#define Hx 16
#define Sx 4096
#define HDx 64
#define NF 9
#define NH (Bx*Hx)                 // 64 heads
#define NCH 16                     // S-chunks per head for kernel 1/2
#define TOK_PER_BLOCK (Sx/NCH)     // 256
#define TOK_PER_WAVE (TOK_PER_BLOCK/4)  // 64

__device__ __forceinline__ float lane_bcast(float x, int l) {
    return __int_as_float(__builtin_amdgcn_readlane(__float_as_int(x), l));
}

// ---------------------------------------------------------------------------
// Kernel 1: KV[head][d][e] = sum_s (K_t - lam_k*K')[s,d] * V[s,e]
// wave-per-token; lane owns column e = lane. Partial KV atomically added.
// ---------------------------------------------------------------------------
__global__ __launch_bounds__(256) void kv_kernel(
    const float* __restrict__ Kt, const float* __restrict__ Kp,
    const float* __restrict__ V,  const float* __restrict__ lambdas,
    const float* __restrict__ Wk, float* __restrict__ KV)
{
    const int tid  = threadIdx.x;
    const int lane = tid & 63;
    const int wave = tid >> 6;
    const int head  = blockIdx.x & (NH - 1);
    const int chunk = blockIdx.x >> 6;           // / NH
    const size_t base = (size_t)head * Sx * HDx;
    const int s0 = chunk * TOK_PER_BLOCK + wave * TOK_PER_WAVE;

    // per-lane router weights: score_n = sum_l kt_l*Wk[n,l] + kp_l*Wk[n,64+l]
    float w0[NF], w1[NF];
#pragma unroll
    for (int n = 0; n < NF; ++n) {
        w0[n] = Wk[n * 128 + lane];
        w1[n] = Wk[n * 128 + 64 + lane];
    }

    __shared__ float lam_s[16];
    __shared__ float red[HDx * 64];   // 16 KB cross-wave reduce buffer
    if (tid < NF) lam_s[tid] = lambdas[tid];
    __syncthreads();

    float acc[HDx];
#pragma unroll
    for (int d = 0; d < HDx; ++d) acc[d] = 0.f;

    for (int i = 0; i < TOK_PER_WAVE; ++i) {
        const size_t row = base + (size_t)(s0 + i) * HDx;
        const float kt = Kt[row + lane];
        const float kp = Kp[row + lane];
        const float v  = V [row + lane];

        // router scores: per-lane partials, butterfly reduce over 64 lanes
        float sc[NF];
#pragma unroll
        for (int n = 0; n < NF; ++n) sc[n] = kt * w0[n] + kp * w1[n];
#pragma unroll
        for (int m = 1; m < 64; m <<= 1) {
#pragma unroll
            for (int n = 0; n < NF; ++n) sc[n] += __shfl_xor(sc[n], m, 64);
        }
        // argmax, first max wins (matches jnp.argmax)
        int bi = 0; float bv = sc[0];
#pragma unroll
        for (int n = 1; n < NF; ++n) { if (sc[n] > bv) { bv = sc[n]; bi = n; } }
        const float lam = lam_s[bi];
        const float kd  = kt - lam * kp;

        // rank-1 update: acc[d] += kd(d) * v(e=lane)
#pragma unroll
        for (int d = 0; d < HDx; ++d)
            acc[d] = fmaf(lane_bcast(kd, d), v, acc[d]);
    }

    // reduce waves 1..3 into wave 0 through LDS
    for (int w = 1; w < 4; ++w) {
        if (wave == w) {
#pragma unroll
            for (int d = 0; d < HDx; ++d) red[d * 64 + lane] = acc[d];
        }
        __syncthreads();
        if (wave == 0) {
#pragma unroll
            for (int d = 0; d < HDx; ++d) acc[d] += red[d * 64 + lane];
        }
        __syncthreads();
    }
    if (wave == 0) {
        float* kvh = KV + head * (HDx * HDx);
#pragma unroll
        for (int d = 0; d < HDx; ++d)
            atomicAdd(kvh + d * 64 + lane, acc[d]);
    }
}

// ---------------------------------------------------------------------------
// Kernel 2: O[s,e] = sum_d (Q_t - lam_q*Q')[s,d] * KV[d,e]
// lane owns column e = lane; KV column cached in 64 VGPRs.
// ---------------------------------------------------------------------------
__global__ __launch_bounds__(256) void out_kernel(
    const float* __restrict__ Qt, const float* __restrict__ Qp,
    const float* __restrict__ lambdas, const float* __restrict__ Wq,
    const float* __restrict__ KV, float* __restrict__ O)
{
    const int tid  = threadIdx.x;
    const int lane = tid & 63;
    const int wave = tid >> 6;
    const int head  = blockIdx.x & (NH - 1);
    const int chunk = blockIdx.x >> 6;
    const size_t base = (size_t)head * Sx * HDx;
    const int s0 = chunk * TOK_PER_BLOCK + wave * TOK_PER_WAVE;

    float w0[NF], w1[NF];
#pragma unroll
    for (int n = 0; n < NF; ++n) {
        w0[n] = Wq[n * 128 + lane];
        w1[n] = Wq[n * 128 + 64 + lane];
    }

    __shared__ float lam_s[16];
    if (tid < NF) lam_s[tid] = lambdas[tid];

    // cache this head's KV column e=lane: kv[d] = KV[head][d][lane]
    float kv[HDx];
    const float* kvh = KV + head * (HDx * HDx);
#pragma unroll
    for (int d = 0; d < HDx; ++d) kv[d] = kvh[d * 64 + lane];
    __syncthreads();

    for (int i = 0; i < TOK_PER_WAVE; ++i) {
        const size_t row = base + (size_t)(s0 + i) * HDx;
        const float qt = Qt[row + lane];
        const float qp = Qp[row + lane];

        float sc[NF];
#pragma unroll
        for (int n = 0; n < NF; ++n) sc[n] = qt * w0[n] + qp * w1[n];
#pragma unroll
        for (int m = 1; m < 64; m <<= 1) {
#pragma unroll
            for (int n = 0; n < NF; ++n) sc[n] += __shfl_xor(sc[n], m, 64);
        }
        int bi = 0; float bv = sc[0];
#pragma unroll
        for (int n = 1; n < NF; ++n) { if (sc[n] > bv) { bv = sc[n]; bi = n; } }
        const float lam = lam_s[bi];
        const float qd  = qt - lam * qp;

        float o = 0.f;
#pragma unroll
        for (int d = 0; d < HDx; ++d)
            o = fmaf(lane_bcast(qd, d), kv[d], o);

        O[row + lane] = o;
    }
}

// ---------------------------------------------------------------------------
extern "C" void kernel_launch(void* const* d_in, const int* in_sizes, int n_in,
                              void* d_out, int out_size, void* d_ws, size_t ws_size,
                              hipStream_t stream) {
    const float* Qt      = (const float*)d_in[0];
    const float* Qp      = (const float*)d_in[1];
    const float* Kt      = (const float*)d_in[2];
    const float* Kp      = (const float*)d_in[3];
    const float* V       = (const float*)d_in[4];
    const float* lambdas = (const float*)d_in[5];
    const float* Wq      = (const float*)d_in[6];
    const float* Wk      = (const float*)d_in[7];
    float* O  = (float*)d_out;
    float* KV = (float*)d_ws;   // NH * 64 * 64 floats = 1 MB

    hipMemsetAsync(d_ws, 0, (size_t)NH * HDx * HDx * sizeof(float), stream);
    kv_kernel <<<NH * NCH, 256, 0, stream>>>(Kt, Kp, V, lambdas, Wk, KV);
    out_kernel<<<NH * NCH, 256, 0, stream>>>(Qt, Qp, lambdas, Wq, KV, O);
}

// Round 2
// 382.495 us; speedup vs baseline: 1.4713x; 1.4713x over previous
//
#include <hip/hip_runtime.h>

#define Sx 4096
#define HDx 64
#define NF 9
#define NHEAD 64
#define NCH 16
#define SC (Sx / NCH)      // 256 tokens per block
#define NTILE (SC / 64)    // 4 tiles of 64 tokens
#define LROW 72            // padded LDS row stride (bf16 units); 144 B = 16B-aligned

typedef __attribute__((ext_vector_type(8))) short bf16x8;
typedef __attribute__((ext_vector_type(4))) float f32x4;

__device__ __forceinline__ unsigned short f2bf(float f) {
    union { float f; unsigned u; } x; x.f = f;
    unsigned r = x.u + 0x7fffu + ((x.u >> 16) & 1u);   // RNE
    return (unsigned short)(r >> 16);
}
__device__ __forceinline__ float bf2f(unsigned short b) {
    union { unsigned u; float f; } x; x.u = ((unsigned)b) << 16;
    return x.f;
}
__device__ __forceinline__ unsigned long long pack4(float4 v) {
    return (unsigned long long)f2bf(v.x)
         | ((unsigned long long)f2bf(v.y) << 16)
         | ((unsigned long long)f2bf(v.z) << 32)
         | ((unsigned long long)f2bf(v.w) << 48);
}

// ---------------------------------------------------------------------------
// Kernel 1: KVt[head][e][d] += sum_s (Kt - lam*Kp)[s,d] * V[s,e]
// GEMM M=d(64) N=e(64) K=s; wave = N-tile (16 e-cols), 4 M-tiles per wave.
// ---------------------------------------------------------------------------
__global__ __launch_bounds__(256) void kv_kernel(
    const float* __restrict__ Kt, const float* __restrict__ Kp,
    const float* __restrict__ V,  const float* __restrict__ lambdas,
    const float* __restrict__ Wk, float* __restrict__ KVt)
{
    __shared__ __align__(16) unsigned short kt_s[64][LROW];
    __shared__ __align__(16) unsigned short kp_s[64][LROW];
    __shared__ __align__(16) unsigned short kd_s[64][LROW];   // [d][s]
    __shared__ float lam_s[64];
    __shared__ float lam9[16];

    const int tid  = threadIdx.x;
    const int lane = tid & 63;
    const int wave = tid >> 6;
    const int l15  = lane & 15;
    const int q    = lane >> 4;
    const int head  = blockIdx.x & (NHEAD - 1);
    const int chunk = blockIdx.x >> 6;
    const size_t hbase = (size_t)head * Sx * HDx;
    const int sbase = chunk * SC;

    if (tid < NF) lam9[tid] = lambdas[tid];

    // Router-weight B-frags: B[k=cat-feat][n=router]; cols 9..15 zero.
    bf16x8 wb[4];
#pragma unroll
    for (int h = 0; h < 4; ++h)
#pragma unroll
        for (int j = 0; j < 8; ++j) {
            float w = (l15 < NF) ? Wk[l15 * 128 + h * 32 + q * 8 + j] : 0.f;
            wb[h][j] = (short)f2bf(w);
        }

    f32x4 acc[4];
#pragma unroll
    for (int mt = 0; mt < 4; ++mt) acc[mt] = (f32x4){0.f, 0.f, 0.f, 0.f};

    const int tok = tid >> 2;          // 0..63 (wave-local: wave w owns toks 16w..)
    const int fb  = (tid & 3) * 16;

    for (int t = 0; t < NTILE; ++t) {
        const int s0 = sbase + t * 64;
        // ---- global loads (fp32, coalesced float4) ----
        const float4* pkt = (const float4*)(Kt + hbase + (size_t)(s0 + tok) * HDx + fb);
        const float4* pkp = (const float4*)(Kp + hbase + (size_t)(s0 + tok) * HDx + fb);
        float4 ka[4], kb[4];
#pragma unroll
        for (int i = 0; i < 4; ++i) { ka[i] = pkt[i]; kb[i] = pkp[i]; }
        // V directly in B-frag layout: e-col = wave*16 + l15
        const int ecol = wave * 16 + l15;
        float vv[16];
#pragma unroll
        for (int h = 0; h < 2; ++h)
#pragma unroll
            for (int j = 0; j < 8; ++j)
                vv[h * 8 + j] = V[hbase + (size_t)(s0 + h * 32 + q * 8 + j) * HDx + ecol];
        // ---- stage Kt/Kp as bf16 ----
#pragma unroll
        for (int i = 0; i < 4; ++i) {
            *(unsigned long long*)&kt_s[tok][fb + 4 * i] = pack4(ka[i]);
            *(unsigned long long*)&kp_s[tok][fb + 4 * i] = pack4(kb[i]);
        }
        __syncthreads();
        // ---- scores via MFMA: wave scores its own 16 tokens ----
        const int mrow = wave * 16 + l15;
        bf16x8 af[4];
        af[0] = *(const bf16x8*)&kt_s[mrow][q * 8];
        af[1] = *(const bf16x8*)&kt_s[mrow][32 + q * 8];
        af[2] = *(const bf16x8*)&kp_s[mrow][q * 8];
        af[3] = *(const bf16x8*)&kp_s[mrow][32 + q * 8];
        f32x4 sc = (f32x4){0.f, 0.f, 0.f, 0.f};
#pragma unroll
        for (int h = 0; h < 4; ++h)
            sc = __builtin_amdgcn_mfma_f32_16x16x32_bf16(af[h], wb[h], sc, 0, 0, 0);
        // argmax over n (lanes 0..8 of each 16-group), first-max-wins
        float lamr[4];
#pragma unroll
        for (int r = 0; r < 4; ++r) {
            float v = (l15 < NF) ? sc[r] : -3.4e38f;
            int idx = l15;
#pragma unroll
            for (int m = 1; m < 16; m <<= 1) {
                float ov = __shfl_xor(v, m, 16);
                int   oi = __shfl_xor(idx, m, 16);
                bool take = (ov > v) || (ov == v && oi < idx);
                v = take ? ov : v; idx = take ? oi : idx;
            }
            lamr[r] = lam9[idx];
        }
        if (l15 == 0) {
#pragma unroll
            for (int r = 0; r < 4; ++r) lam_s[wave * 16 + q * 4 + r] = lamr[r];
        }
        __syncthreads();
        // ---- K_diff, written transposed [d][s] ----
        {
            const float lam = lam_s[tok];
#pragma unroll
            for (int i = 0; i < 4; ++i) {
                const float* a = (const float*)&ka[i];
                const float* b = (const float*)&kb[i];
#pragma unroll
                for (int jj = 0; jj < 4; ++jj)
                    kd_s[fb + 4 * i + jj][tok] = f2bf(a[jj] - lam * b[jj]);
            }
        }
        __syncthreads();
        // ---- KV MFMA ----
#pragma unroll
        for (int h = 0; h < 2; ++h) {
            bf16x8 bv;
#pragma unroll
            for (int j = 0; j < 8; ++j) bv[j] = (short)f2bf(vv[h * 8 + j]);
#pragma unroll
            for (int mt = 0; mt < 4; ++mt) {
                bf16x8 ad = *(const bf16x8*)&kd_s[mt * 16 + l15][h * 32 + q * 8];
                acc[mt] = __builtin_amdgcn_mfma_f32_16x16x32_bf16(ad, bv, acc[mt], 0, 0, 0);
            }
        }
        __syncthreads();
    }
    // ---- epilogue: atomic accumulate into transposed KVt[e][d] ----
    float* kvh = KVt + head * (HDx * HDx);
#pragma unroll
    for (int mt = 0; mt < 4; ++mt)
#pragma unroll
        for (int r = 0; r < 4; ++r) {
            const int d = mt * 16 + q * 4 + r;
            const int e = wave * 16 + l15;
            atomicAdd(&kvh[e * 64 + d], acc[mt][r]);
        }
}

// ---------------------------------------------------------------------------
// Kernel 2: O[s,e] = sum_d (Qt - lam*Qp)[s,d] * KV[d,e]
// GEMM M=tokens N=e(64) K=d(64); wave = M-tile (its 16 tokens), 4 N-tiles.
// ---------------------------------------------------------------------------
__global__ __launch_bounds__(256) void out_kernel(
    const float* __restrict__ Qt, const float* __restrict__ Qp,
    const float* __restrict__ lambdas, const float* __restrict__ Wq,
    const float* __restrict__ KVt, float* __restrict__ O)
{
    __shared__ __align__(16) unsigned short qt_s[64][LROW];
    __shared__ __align__(16) unsigned short qp_s[64][LROW];
    __shared__ float lam_s[64];
    __shared__ float lam9[16];

    const int tid  = threadIdx.x;
    const int lane = tid & 63;
    const int wave = tid >> 6;
    const int l15  = lane & 15;
    const int q    = lane >> 4;
    const int head  = blockIdx.x & (NHEAD - 1);
    const int chunk = blockIdx.x >> 6;
    const size_t hbase = (size_t)head * Sx * HDx;
    const int sbase = chunk * SC;

    if (tid < NF) lam9[tid] = lambdas[tid];

    bf16x8 wb[4];
#pragma unroll
    for (int h = 0; h < 4; ++h)
#pragma unroll
        for (int j = 0; j < 8; ++j) {
            float w = (l15 < NF) ? Wq[l15 * 128 + h * 32 + q * 8 + j] : 0.f;
            wb[h][j] = (short)f2bf(w);
        }

    // Preload KV B-frags once per block: B[k=d][n=e] from KVt[e][d]
    bf16x8 bkv[4][2];
    const float* kvh = KVt + head * (HDx * HDx);
#pragma unroll
    for (int nt = 0; nt < 4; ++nt)
#pragma unroll
        for (int h = 0; h < 2; ++h)
#pragma unroll
            for (int j = 0; j < 8; ++j)
                bkv[nt][h][j] = (short)f2bf(kvh[(nt * 16 + l15) * 64 + h * 32 + q * 8 + j]);

    const int tok = tid >> 2;
    const int fb  = (tid & 3) * 16;

    for (int t = 0; t < NTILE; ++t) {
        const int s0 = sbase + t * 64;
        const float4* pqt = (const float4*)(Qt + hbase + (size_t)(s0 + tok) * HDx + fb);
        const float4* pqp = (const float4*)(Qp + hbase + (size_t)(s0 + tok) * HDx + fb);
        float4 qa[4], qb[4];
#pragma unroll
        for (int i = 0; i < 4; ++i) { qa[i] = pqt[i]; qb[i] = pqp[i]; }
#pragma unroll
        for (int i = 0; i < 4; ++i) {
            *(unsigned long long*)&qt_s[tok][fb + 4 * i] = pack4(qa[i]);
            *(unsigned long long*)&qp_s[tok][fb + 4 * i] = pack4(qb[i]);
        }
        __syncthreads();
        const int mrow = wave * 16 + l15;
        bf16x8 af[4];
        af[0] = *(const bf16x8*)&qt_s[mrow][q * 8];
        af[1] = *(const bf16x8*)&qt_s[mrow][32 + q * 8];
        af[2] = *(const bf16x8*)&qp_s[mrow][q * 8];
        af[3] = *(const bf16x8*)&qp_s[mrow][32 + q * 8];
        f32x4 sc = (f32x4){0.f, 0.f, 0.f, 0.f};
#pragma unroll
        for (int h = 0; h < 4; ++h)
            sc = __builtin_amdgcn_mfma_f32_16x16x32_bf16(af[h], wb[h], sc, 0, 0, 0);
        float lamr[4];
#pragma unroll
        for (int r = 0; r < 4; ++r) {
            float v = (l15 < NF) ? sc[r] : -3.4e38f;
            int idx = l15;
#pragma unroll
            for (int m = 1; m < 16; m <<= 1) {
                float ov = __shfl_xor(v, m, 16);
                int   oi = __shfl_xor(idx, m, 16);
                bool take = (ov > v) || (ov == v && oi < idx);
                v = take ? ov : v; idx = take ? oi : idx;
            }
            lamr[r] = lam9[idx];
        }
        if (l15 == 0) {
#pragma unroll
            for (int r = 0; r < 4; ++r) lam_s[wave * 16 + q * 4 + r] = lamr[r];
        }
        __syncthreads();
        // A-frags for the out-GEMM reuse the score frags (same lane mapping)
        const float lamv = lam_s[mrow];
        f32x4 oacc[4];
#pragma unroll
        for (int nt = 0; nt < 4; ++nt) oacc[nt] = (f32x4){0.f, 0.f, 0.f, 0.f};
#pragma unroll
        for (int h = 0; h < 2; ++h) {
            bf16x8 ad;
#pragma unroll
            for (int j = 0; j < 8; ++j) {
                float qd = bf2f((unsigned short)af[h][j])
                         - lamv * bf2f((unsigned short)af[2 + h][j]);
                ad[j] = (short)f2bf(qd);
            }
#pragma unroll
            for (int nt = 0; nt < 4; ++nt)
                oacc[nt] = __builtin_amdgcn_mfma_f32_16x16x32_bf16(ad, bkv[nt][h], oacc[nt], 0, 0, 0);
        }
#pragma unroll
        for (int nt = 0; nt < 4; ++nt)
#pragma unroll
            for (int r = 0; r < 4; ++r) {
                const int row = s0 + wave * 16 + q * 4 + r;
                O[hbase + (size_t)row * HDx + nt * 16 + l15] = oacc[nt][r];
            }
        __syncthreads();
    }
}

// ---------------------------------------------------------------------------
extern "C" void kernel_launch(void* const* d_in, const int* in_sizes, int n_in,
                              void* d_out, int out_size, void* d_ws, size_t ws_size,
                              hipStream_t stream) {
    const float* Qt      = (const float*)d_in[0];
    const float* Qp      = (const float*)d_in[1];
    const float* Kt      = (const float*)d_in[2];
    const float* Kp      = (const float*)d_in[3];
    const float* V       = (const float*)d_in[4];
    const float* lambdas = (const float*)d_in[5];
    const float* Wq      = (const float*)d_in[6];
    const float* Wk      = (const float*)d_in[7];
    float* O  = (float*)d_out;
    float* KV = (float*)d_ws;   // 64 heads * 64 * 64 fp32 = 1 MB (KVt: [e][d])

    hipMemsetAsync(d_ws, 0, (size_t)NHEAD * HDx * HDx * sizeof(float), stream);
    kv_kernel <<<NHEAD * NCH, 256, 0, stream>>>(Kt, Kp, V, lambdas, Wk, KV);
    out_kernel<<<NHEAD * NCH, 256, 0, stream>>>(Qt, Qp, lambdas, Wq, KV, O);
}